// Round 7
// baseline (242.079 us; speedup 1.0000x reference)
//
#include <hip/hip_runtime.h>
#include <stdint.h>

// Problem constants (fixed by setup_inputs).
#define N_LIDAR   8192
#define M_QUERIES 32768   // 1024 rays * 32 samples
#define D_FEAT    128
#define BLOCK     256
#define SEG1      1024                     // p1 candidates per block
#define NSEG1     (N_LIDAR / SEG1)         // 8
#define SEG2      512                      // p2 candidates per block
#define NSEG2     (N_LIDAR / SEG2)         // 16
#define N_QBLK    (M_QUERIES / BLOCK)      // 128 query-blocks (256 queries each)

// Filter slack (one-sided approx error, doubled) — HW-proven in prior session.
#define EPS2 0.008f

typedef __attribute__((ext_vector_type(8)))  short bf16x8;
typedef __attribute__((ext_vector_type(16))) float f32x16;

// Workspace layout (~2.25 MB):
#define WS_KEYS  0                         // 32768 * 8  u64 exact argmin keys
#define WS_GMIN  262144                    // 32768 * 4  u32 mapped approx mins
#define WS_ATAB  393216                    // 32768 * 16 bf16 (32B rows)
#define WS_BTAB  1441792                   //  8192 * 16 bf16 (32B rows)
#define WS_QPK   1703936                   // 32768 float4 (x,y,z,qs)
#define WS_CPK   2228224                   //  8192 float4 (-2lx,-2ly,-2lz,ks)
#define WS_CNT   2359296                   //   128 * 4   u32 per-qblock done counters

// Order-preserving float->u32 map (and inverse) for atomicMin.
__device__ __forceinline__ unsigned mapf(float f) {
    unsigned u = __float_as_uint(f);
    return (u & 0x80000000u) ? ~u : (u | 0x80000000u);
}
__device__ __forceinline__ float unmapf(unsigned u) {
    return __uint_as_float((u & 0x80000000u) ? (u ^ 0x80000000u) : ~u);
}

// Split f32 into bf16 hi + bf16 lo (RNE).
__device__ __forceinline__ void bsplit(float v, short& h, short& l) {
    unsigned u = __float_as_uint(v);
    unsigned r = (u + 0x7FFFu + ((u >> 16) & 1u)) & 0xFFFF0000u;
    h = (short)(r >> 16);
    float lo = v - __uint_as_float(r);
    unsigned u2 = __float_as_uint(lo);
    l = (short)((u2 + 0x7FFFu + ((u2 >> 16) & 1u)) >> 16);
}

#define BF_ONE ((short)0x3F80)

// Plain fminf tree over 16 regs (HW-verified bitwise in r1/r2 diagnostics).
__device__ __forceinline__ float vmin16_plain(const f32x16& v) {
    float a0 = fminf(v[0],  v[1]),  a1 = fminf(v[2],  v[3]);
    float a2 = fminf(v[4],  v[5]),  a3 = fminf(v[6],  v[7]);
    float a4 = fminf(v[8],  v[9]),  a5 = fminf(v[10], v[11]);
    float a6 = fminf(v[12], v[13]), a7 = fminf(v[14], v[15]);
    float b0 = fminf(a0, a1), b1 = fminf(a2, a3);
    float b2 = fminf(a4, a5), b3 = fminf(a6, a7);
    return fminf(fminf(b0, b1), fminf(b2, b3));
}

// Prep: build MFMA A/B tables encoding e_a ~= -2*q.l + ks (argmin of d2 ==
// argmin of e since qs is a per-query constant), exact-rescore packs,
// init gmin/keys/cnt. (r5 lesson: keep these tables GLOBAL and precomputed —
// per-block LDS rebuild was an 8x regression.)
__global__ __launch_bounds__(BLOCK)
void prep_kernel(const float* __restrict__ pts, const float* __restrict__ lidar,
                 short* __restrict__ Atab, short* __restrict__ Btab,
                 float4* __restrict__ qpack, float4* __restrict__ cpack,
                 unsigned* __restrict__ gmin, unsigned long long* __restrict__ keys,
                 unsigned* __restrict__ cnt) {
    #pragma clang fp contract(off)
    int i = blockIdx.x * blockDim.x + threadIdx.x;
    if (threadIdx.x == 0) cnt[blockIdx.x] = 0u;   // grid = 128 = N_QBLK

    { // query side (all 32768)
        float x = pts[3 * i + 0], y = pts[3 * i + 1], z = pts[3 * i + 2];
        float qs = (x * x + y * y) + z * z;     // np rounding order, no FMA
        short xh, xl, yh, yl, zh, zl;
        bsplit(x, xh, xl); bsplit(y, yh, yl); bsplit(z, zh, zl);
        short a[16] = {xh, xh, xl, yh, yh, yl, zh, zh, zl,
                       BF_ONE, BF_ONE, 0, 0, 0, 0, 0};
        ((int4*)(Atab + 16 * i))[0] = *(const int4*)(a);
        ((int4*)(Atab + 16 * i))[1] = *(const int4*)(a + 8);
        qpack[i] = make_float4(x, y, z, qs);
        gmin[i]  = 0xFFFFFFFFu;
        keys[i]  = 0xFFFFFFFFFFFFFFFFull;
    }
    if (i < N_LIDAR) {
        float lx = lidar[3 * i + 0], ly = lidar[3 * i + 1], lz = lidar[3 * i + 2];
        float ks = (lx * lx + ly * ly) + lz * lz;   // np rounding order
        float Lx = -2.0f * lx, Ly = -2.0f * ly, Lz = -2.0f * lz;  // exact
        short xh, xl, yh, yl, zh, zl, kh, kl;
        bsplit(Lx, xh, xl); bsplit(Ly, yh, yl); bsplit(Lz, zh, zl); bsplit(ks, kh, kl);
        short b[16] = {xh, xl, xh, yh, yl, yh, zh, zl, zh,
                       kh, kl, 0, 0, 0, 0, 0};
        ((int4*)(Btab + 16 * i))[0] = *(const int4*)(b);
        ((int4*)(Btab + 16 * i))[1] = *(const int4*)(b + 8);
        cpack[i] = make_float4(Lx, Ly, Lz, ks);
    }
}

// MFMA fragment addressing for v_mfma_f32_32x32x16_bf16 (HW-proven):
//   A[m][k]: m = lane&31, k = (lane>>5)*8 + j
//   B[k][n]: n = lane&31, k = (lane>>5)*8 + j
//   C/D    : col = lane&31, row = (reg&3) + 8*(reg>>2) + 4*(lane>>5)
// TRANSPOSED FORM (r1/r2 HW-verified bitwise): mfma(cand_frag, query_frag)
// -> D[row=candidate][col=query], per-pair bitwise equal. Queries lane-local.

// P1 (r1-verified, live since r3): per-query min of e_a over a 1024-candidate
// stripe -> atomicMin gmin. Per-lane min tree, one xor-32 merge, 64 atomics.
__global__ __launch_bounds__(BLOCK, 4)
void p1_kernel(const short* __restrict__ Atab, const short* __restrict__ Btab,
               unsigned* __restrict__ gmin) {
    const int lane = threadIdx.x & 63, wave = threadIdx.x >> 6;
    const int half = lane >> 5, ln = lane & 31;
    const int qbase = blockIdx.x * 256 + wave * 64;
    const int segbase = blockIdx.y * SEG1;

    bf16x8 q0 = *(const bf16x8*)(Atab + (qbase + ln) * 16 + half * 8);
    bf16x8 q1 = *(const bf16x8*)(Atab + (qbase + 32 + ln) * 16 + half * 8);
    float m0 = __builtin_inff(), m1 = __builtin_inff();

    const short* cp = Btab + (segbase + ln) * 16 + half * 8;
    #pragma unroll 2
    for (int g = 0; g < SEG1 / 32; ++g) {
        bf16x8 c = *(const bf16x8*)cp;
        cp += 32 * 16;
        f32x16 z = 0.0f;
        f32x16 acc0 = __builtin_amdgcn_mfma_f32_32x32x16_bf16(c, q0, z, 0, 0, 0);
        f32x16 acc1 = __builtin_amdgcn_mfma_f32_32x32x16_bf16(c, q1, z, 0, 0, 0);
        m0 = fminf(m0, vmin16_plain(acc0));
        m1 = fminf(m1, vmin16_plain(acc1));
    }

    // Lanes ln / ln+32 hold the two half-sets of candidate rows of the same
    // query column -> one xor-32 merge completes the stripe min.
    m0 = fminf(m0, __shfl_xor(m0, 32));
    m1 = fminf(m1, __shfl_xor(m1, 32));

    if (half == 0) atomicMin(&gmin[qbase + ln],      mapf(m0));
    else           atomicMin(&gmin[qbase + 32 + ln], mapf(m1));
}

// Exact reference-rounded rescore of one (query, candidate) pair (proven).
__device__ __forceinline__ void rescore(int q, int c,
                                        const float4* __restrict__ qpack,
                                        const float4* __restrict__ cpack,
                                        unsigned long long* __restrict__ keys) {
    #pragma clang fp contract(off)
    float4 Q = qpack[q];
    float4 C = cpack[c];
    float cr = (Q.x * C.x + Q.y * C.y) + Q.z * C.z;  // = -2*cross, bit-exact
    float t  = Q.w + cr;                             // = fl(qs - 2*cross)
    float d2 = t + C.w;                              // = fl(t + ks)
    unsigned u = __float_as_uint(d2);
    u ^= (u >> 31) ? 0xFFFFFFFFu : 0x80000000u;
    unsigned long long key = ((unsigned long long)u << 13) | (unsigned)c;
    atomicMin(&keys[q], key);   // ties -> smaller index (np.argmin semantics)
}

// P2 (r2-verified transposed form, live since r3) + fused gather epilogue
// (pattern proven correct in r5: absmax 0.0). Fast path = 2 MFMA +
// 2x(min tree + 1 cmp) + __any. Slow path: per-reg hit masks, exact rescore.
//
// Epilogue ordering (r4 race lesson):
//   (a) __syncthreads — ALL warps issued+drained their rescore atomics
//       (barrier implies vmcnt(0) per wave),
//   (b) __threadfence — device visibility,
//   (c) tid 0 takes the atomicAdd ticket; last block gathers.
__global__ __launch_bounds__(BLOCK, 4)
void p2_kernel(const short* __restrict__ Atab, const short* __restrict__ Btab,
               const unsigned* __restrict__ gmin,
               const float4* __restrict__ qpack, const float4* __restrict__ cpack,
               unsigned long long* __restrict__ keys, unsigned* __restrict__ cnt,
               const float4* __restrict__ feat, float4* __restrict__ out) {
    __shared__ int sidx[256];
    __shared__ int lastFlag;
    const int tid = threadIdx.x;
    const int lane = tid & 63, wave = tid >> 6;
    const int half = lane >> 5, ln = lane & 31;
    const int bx = blockIdx.x;
    const int qb0 = bx * 256;
    const int qbase = qb0 + wave * 64;
    const int segbase = blockIdx.y * SEG2;

    bf16x8 q0 = *(const bf16x8*)(Atab + (qbase + ln) * 16 + half * 8);
    bf16x8 q1 = *(const bf16x8*)(Atab + (qbase + 32 + ln) * 16 + half * 8);
    const float thr0 = unmapf(gmin[qbase + ln]) + EPS2;        // per-lane query thr
    const float thr1 = unmapf(gmin[qbase + 32 + ln]) + EPS2;

    const short* cp = Btab + (segbase + ln) * 16 + half * 8;
    for (int g = 0; g < SEG2 / 32; ++g) {
        bf16x8 c = *(const bf16x8*)cp;
        cp += 32 * 16;
        f32x16 z = 0.0f;
        f32x16 acc0 = __builtin_amdgcn_mfma_f32_32x32x16_bf16(c, q0, z, 0, 0, 0);
        f32x16 acc1 = __builtin_amdgcn_mfma_f32_32x32x16_bf16(c, q1, z, 0, 0, 0);
        float t0 = vmin16_plain(acc0);
        float t1 = vmin16_plain(acc1);
        // min_r(acc[r]) < thr  <=>  exists r: acc[r] < thr.
        if (__any((t0 < thr0) | (t1 < thr1))) {
            const int cbase = segbase + g * 32 + 4 * half;
            unsigned mk0 = 0, mk1 = 0;
            #pragma unroll
            for (int r = 0; r < 16; ++r) mk0 = (acc0[r] < thr0) ? (mk0 | (1u << r)) : mk0;
            #pragma unroll
            for (int r = 0; r < 16; ++r) mk1 = (acc1[r] < thr1) ? (mk1 | (1u << r)) : mk1;
            while (mk0) {   // only hitting lanes iterate (exec-masked)
                int r = __builtin_ctz(mk0); mk0 &= mk0 - 1;
                rescore(qbase + ln, cbase + (r & 3) + 8 * (r >> 2),
                        qpack, cpack, keys);
            }
            while (mk1) {
                int r = __builtin_ctz(mk1); mk1 &= mk1 - 1;
                rescore(qbase + 32 + ln, cbase + (r & 3) + 8 * (r >> 2),
                        qpack, cpack, keys);
            }
        }
    }

    // --- fused gather: last block of this qblock finishes the 256 queries ---
    __syncthreads();       // (a)
    __threadfence();       // (b)
    if (tid == 0) lastFlag = (atomicAdd(&cnt[bx], 1u) == (unsigned)(NSEG2 - 1));
    __syncthreads();
    if (lastFlag) {
        // Atomic RMW fetch of the final key (coherent, no stale reads).
        unsigned long long k = atomicMin(&keys[qb0 + tid], 0xFFFFFFFFFFFFFFFFull);
        sidx[tid] = (int)(k & (unsigned long long)(N_LIDAR - 1));
        __syncthreads();
        const int l32 = tid & 31, grp = tid >> 5;   // 8 query-groups of 32 lanes
        #pragma unroll 4
        for (int p = 0; p < 32; ++p) {
            int ql = p * 8 + grp;
            int idx = sidx[ql];
            out[(qb0 + ql) * (D_FEAT / 4) + l32] = feat[idx * (D_FEAT / 4) + l32];
        }
    }
}

extern "C" void kernel_launch(void* const* d_in, const int* in_sizes, int n_in,
                              void* d_out, int out_size, void* d_ws, size_t ws_size,
                              hipStream_t stream) {
    const float* pts      = (const float*)d_in[0];   // (1,1024,32,3)
    const float* lidar    = (const float*)d_in[1];   // (1,8192,3)
    const float* features = (const float*)d_in[2];   // (1,8192,128)
    float* out = (float*)d_out;                      // (1,1024,32,128)

    char* ws = (char*)d_ws;
    unsigned long long* keys = (unsigned long long*)(ws + WS_KEYS);
    unsigned* gmin = (unsigned*)(ws + WS_GMIN);
    short* Atab = (short*)(ws + WS_ATAB);
    short* Btab = (short*)(ws + WS_BTAB);
    float4* qpack = (float4*)(ws + WS_QPK);
    float4* cpack = (float4*)(ws + WS_CPK);
    unsigned* cnt = (unsigned*)(ws + WS_CNT);

    prep_kernel<<<N_QBLK, BLOCK, 0, stream>>>(pts, lidar, Atab, Btab,
                                              qpack, cpack, gmin, keys, cnt);
    p1_kernel<<<dim3(N_QBLK, NSEG1), BLOCK, 0, stream>>>(Atab, Btab, gmin);
    p2_kernel<<<dim3(N_QBLK, NSEG2), BLOCK, 0, stream>>>(
        Atab, Btab, gmin, qpack, cpack, keys, cnt,
        (const float4*)features, (float4*)out);
}

// Round 9
// 122.545 us; speedup vs baseline: 1.9754x; 1.9754x over previous
//
#include <hip/hip_runtime.h>
#include <stdint.h>

// Problem constants (fixed by setup_inputs).
#define N_LIDAR   8192
#define M_QUERIES 32768   // 1024 rays * 32 samples
#define D_FEAT    128
#define BLOCK     256
#define SEG1      1024                     // p1 candidates per block
#define NSEG1     (N_LIDAR / SEG1)         // 8
#define SEG2      512                      // p2 candidates per block
#define NSEG2     (N_LIDAR / SEG2)         // 16
#define N_QBLK    (M_QUERIES / BLOCK)      // 128 query-blocks (256 queries each)

// Filter slack (one-sided approx error, doubled) — HW-proven in prior session.
#define EPS2 0.008f

typedef __attribute__((ext_vector_type(8)))  short bf16x8;
typedef __attribute__((ext_vector_type(16))) float f32x16;

// Workspace layout (2.25 MB):
#define WS_KEYS  0                         // 32768 * 8  u64 exact argmin keys
#define WS_GMIN  262144                    // 32768 * 4  u32 mapped approx mins
#define WS_ATAB  393216                    // 32768 * 16 bf16 (32B rows)
#define WS_BTAB  1441792                   //  8192 * 16 bf16 (32B rows)
#define WS_QPK   1703936                   // 32768 float4 (x,y,z,qs)
#define WS_CPK   2228224                   //  8192 float4 (-2lx,-2ly,-2lz,ks)

// SESSION LESSONS (HW-proven, do not re-attempt):
//  - r5: per-block LDS fragment rebuild = 39x redundant build work (67 us k1).
//    Tables must stay global + precomputed (L2-resident, ~8 us readers).
//  - r5/r6: last-block fused gather needs __threadfence per block; on gfx950
//    an agent-scope fence = L2 writeback+invalidate (non-coherent per-XCD
//    L2s) -> ~150 us across 2048 blocks. Launch-count reduction via
//    cross-block sync is net-negative. 4 launches is the structural optimum.

// Order-preserving float->u32 map (and inverse) for atomicMin.
__device__ __forceinline__ unsigned mapf(float f) {
    unsigned u = __float_as_uint(f);
    return (u & 0x80000000u) ? ~u : (u | 0x80000000u);
}
__device__ __forceinline__ float unmapf(unsigned u) {
    return __uint_as_float((u & 0x80000000u) ? (u ^ 0x80000000u) : ~u);
}

// Split f32 into bf16 hi + bf16 lo (RNE).
__device__ __forceinline__ void bsplit(float v, short& h, short& l) {
    unsigned u = __float_as_uint(v);
    unsigned r = (u + 0x7FFFu + ((u >> 16) & 1u)) & 0xFFFF0000u;
    h = (short)(r >> 16);
    float lo = v - __uint_as_float(r);
    unsigned u2 = __float_as_uint(lo);
    l = (short)((u2 + 0x7FFFu + ((u2 >> 16) & 1u)) >> 16);
}

#define BF_ONE ((short)0x3F80)

// Plain fminf tree over 16 regs (HW-verified bitwise in r1/r2 diagnostics).
__device__ __forceinline__ float vmin16_plain(const f32x16& v) {
    float a0 = fminf(v[0],  v[1]),  a1 = fminf(v[2],  v[3]);
    float a2 = fminf(v[4],  v[5]),  a3 = fminf(v[6],  v[7]);
    float a4 = fminf(v[8],  v[9]),  a5 = fminf(v[10], v[11]);
    float a6 = fminf(v[12], v[13]), a7 = fminf(v[14], v[15]);
    float b0 = fminf(a0, a1), b1 = fminf(a2, a3);
    float b2 = fminf(a4, a5), b3 = fminf(a6, a7);
    return fminf(fminf(b0, b1), fminf(b2, b3));
}

// Prep: build MFMA A/B tables encoding e_a ~= -2*q.l + ks (argmin of d2 ==
// argmin of e since qs is a per-query constant), exact-rescore packs,
// init gmin/keys.
//   k0..2 : qx{h,h,l} * Lx{h,l,h}   (L = -2*l, exact power-of-2 scale)
//   k3..5 : qy...,  k6..8 : qz...,  k9,10 : 1 * ks{h,l},  k11..15 : 0
__global__ __launch_bounds__(BLOCK)
void prep_kernel(const float* __restrict__ pts, const float* __restrict__ lidar,
                 short* __restrict__ Atab, short* __restrict__ Btab,
                 float4* __restrict__ qpack, float4* __restrict__ cpack,
                 unsigned* __restrict__ gmin, unsigned long long* __restrict__ keys) {
    #pragma clang fp contract(off)
    int i = blockIdx.x * blockDim.x + threadIdx.x;

    { // query side (all 32768)
        float x = pts[3 * i + 0], y = pts[3 * i + 1], z = pts[3 * i + 2];
        float qs = (x * x + y * y) + z * z;     // np rounding order, no FMA
        short xh, xl, yh, yl, zh, zl;
        bsplit(x, xh, xl); bsplit(y, yh, yl); bsplit(z, zh, zl);
        short a[16] = {xh, xh, xl, yh, yh, yl, zh, zh, zl,
                       BF_ONE, BF_ONE, 0, 0, 0, 0, 0};
        ((int4*)(Atab + 16 * i))[0] = *(const int4*)(a);
        ((int4*)(Atab + 16 * i))[1] = *(const int4*)(a + 8);
        qpack[i] = make_float4(x, y, z, qs);
        gmin[i]  = 0xFFFFFFFFu;
        keys[i]  = 0xFFFFFFFFFFFFFFFFull;
    }
    if (i < N_LIDAR) {
        float lx = lidar[3 * i + 0], ly = lidar[3 * i + 1], lz = lidar[3 * i + 2];
        float ks = (lx * lx + ly * ly) + lz * lz;   // np rounding order
        float Lx = -2.0f * lx, Ly = -2.0f * ly, Lz = -2.0f * lz;  // exact
        short xh, xl, yh, yl, zh, zl, kh, kl;
        bsplit(Lx, xh, xl); bsplit(Ly, yh, yl); bsplit(Lz, zh, zl); bsplit(ks, kh, kl);
        short b[16] = {xh, xl, xh, yh, yl, yh, zh, zl, zh,
                       kh, kl, 0, 0, 0, 0, 0};
        ((int4*)(Btab + 16 * i))[0] = *(const int4*)(b);
        ((int4*)(Btab + 16 * i))[1] = *(const int4*)(b + 8);
        cpack[i] = make_float4(Lx, Ly, Lz, ks);
    }
}

// MFMA fragment addressing for v_mfma_f32_32x32x16_bf16 (HW-proven):
//   A[m][k]: m = lane&31, k = (lane>>5)*8 + j
//   B[k][n]: n = lane&31, k = (lane>>5)*8 + j
//   C/D    : col = lane&31, row = (reg&3) + 8*(reg>>2) + 4*(lane>>5)
//
// TRANSPOSED FORM (HW-verified bitwise in r1 via gmin compare and r2 via
// full exact-key compare): mfma(cand_frag, query_frag) gives
// D[row=candidate][col=query] with per-pair values bitwise equal to the
// original orientation. Queries are lane-local -> per-query candidate
// reduction is a per-lane min tree; p2 threshold is one scalar per lane.

// P1 (r1-verified): per-query min of e_a over a 1024-candidate stripe ->
// atomicMin gmin. Per-lane min tree, one xor-32 merge, 64 parallel atomics.
__global__ __launch_bounds__(BLOCK, 4)
void p1_kernel(const short* __restrict__ Atab, const short* __restrict__ Btab,
               unsigned* __restrict__ gmin) {
    const int lane = threadIdx.x & 63, wave = threadIdx.x >> 6;
    const int half = lane >> 5, ln = lane & 31;
    const int qbase = blockIdx.x * 256 + wave * 64;
    const int segbase = blockIdx.y * SEG1;

    bf16x8 q0 = *(const bf16x8*)(Atab + (qbase + ln) * 16 + half * 8);
    bf16x8 q1 = *(const bf16x8*)(Atab + (qbase + 32 + ln) * 16 + half * 8);
    float m0 = __builtin_inff(), m1 = __builtin_inff();

    const short* cp = Btab + (segbase + ln) * 16 + half * 8;
    #pragma unroll 2
    for (int g = 0; g < SEG1 / 32; ++g) {
        bf16x8 c = *(const bf16x8*)cp;
        cp += 32 * 16;
        f32x16 z = 0.0f;
        f32x16 acc0 = __builtin_amdgcn_mfma_f32_32x32x16_bf16(c, q0, z, 0, 0, 0);
        f32x16 acc1 = __builtin_amdgcn_mfma_f32_32x32x16_bf16(c, q1, z, 0, 0, 0);
        m0 = fminf(m0, vmin16_plain(acc0));
        m1 = fminf(m1, vmin16_plain(acc1));
    }

    // Lanes ln / ln+32 hold the two half-sets of candidate rows of the same
    // query column -> one xor-32 merge completes the 32-row min.
    m0 = fminf(m0, __shfl_xor(m0, 32));
    m1 = fminf(m1, __shfl_xor(m1, 32));

    if (half == 0) atomicMin(&gmin[qbase + ln],      mapf(m0));
    else           atomicMin(&gmin[qbase + 32 + ln], mapf(m1));
}

// Exact reference-rounded rescore of one (query, candidate) pair (proven).
__device__ __forceinline__ void rescore(int q, int c,
                                        const float4* __restrict__ qpack,
                                        const float4* __restrict__ cpack,
                                        unsigned long long* __restrict__ keys) {
    #pragma clang fp contract(off)
    float4 Q = qpack[q];
    float4 C = cpack[c];
    float cr = (Q.x * C.x + Q.y * C.y) + Q.z * C.z;  // = -2*cross, bit-exact
    float t  = Q.w + cr;                             // = fl(qs - 2*cross)
    float d2 = t + C.w;                              // = fl(t + ks)
    unsigned u = __float_as_uint(d2);
    u ^= (u >> 31) ? 0xFFFFFFFFu : 0x80000000u;
    unsigned long long key = ((unsigned long long)u << 13) | (unsigned)c;
    atomicMin(&keys[q], key);   // ties -> smaller index (np.argmin semantics)
}

// P2 (r2-verified transposed form): deterministic re-scan.
// Fast path = 2 MFMA + 2x(min tree + 1 cmp) + __any. Slow path: per-reg hit
// masks, exact rescore of hitting (lane,reg) pairs (exec-masked). Bit-exact
// vs the row=query original (r2: full 32768-key compare, zero mismatches).
__global__ __launch_bounds__(BLOCK, 4)
void p2_kernel(const short* __restrict__ Atab, const short* __restrict__ Btab,
               const unsigned* __restrict__ gmin,
               const float4* __restrict__ qpack, const float4* __restrict__ cpack,
               unsigned long long* __restrict__ keys) {
    const int lane = threadIdx.x & 63, wave = threadIdx.x >> 6;
    const int half = lane >> 5, ln = lane & 31;
    const int qbase = blockIdx.x * 256 + wave * 64;
    const int segbase = blockIdx.y * SEG2;

    bf16x8 q0 = *(const bf16x8*)(Atab + (qbase + ln) * 16 + half * 8);
    bf16x8 q1 = *(const bf16x8*)(Atab + (qbase + 32 + ln) * 16 + half * 8);
    const float thr0 = unmapf(gmin[qbase + ln]) + EPS2;        // per-lane query thr
    const float thr1 = unmapf(gmin[qbase + 32 + ln]) + EPS2;

    const short* cp = Btab + (segbase + ln) * 16 + half * 8;
    for (int g = 0; g < SEG2 / 32; ++g) {
        bf16x8 c = *(const bf16x8*)cp;
        cp += 32 * 16;
        f32x16 z = 0.0f;
        f32x16 acc0 = __builtin_amdgcn_mfma_f32_32x32x16_bf16(c, q0, z, 0, 0, 0);
        f32x16 acc1 = __builtin_amdgcn_mfma_f32_32x32x16_bf16(c, q1, z, 0, 0, 0);
        float t0 = vmin16_plain(acc0);
        float t1 = vmin16_plain(acc1);
        // min_r(acc[r]) < thr  <=>  exists r: acc[r] < thr  (same hit events
        // as the per-reg ballots of the original).
        if (__any((t0 < thr0) | (t1 < thr1))) {
            const int cbase = segbase + g * 32 + 4 * half;
            unsigned mk0 = 0, mk1 = 0;
            #pragma unroll
            for (int r = 0; r < 16; ++r) mk0 = (acc0[r] < thr0) ? (mk0 | (1u << r)) : mk0;
            #pragma unroll
            for (int r = 0; r < 16; ++r) mk1 = (acc1[r] < thr1) ? (mk1 | (1u << r)) : mk1;
            while (mk0) {   // only hitting lanes iterate (exec-masked)
                int r = __builtin_ctz(mk0); mk0 &= mk0 - 1;
                rescore(qbase + ln, cbase + (r & 3) + 8 * (r >> 2),
                        qpack, cpack, keys);
            }
            while (mk1) {
                int r = __builtin_ctz(mk1); mk1 &= mk1 - 1;
                rescore(qbase + 32 + ln, cbase + (r & 3) + 8 * (r >> 2),
                        qpack, cpack, keys);
            }
        }
    }
}

// Gather 128 f32 features per query (32 lanes * float4 per query).
__global__ __launch_bounds__(BLOCK)
void gather_kernel(const unsigned long long* __restrict__ keys,
                   const float4* __restrict__ feat,
                   float4* __restrict__ out) {
    int t    = blockIdx.x * blockDim.x + threadIdx.x;
    int q    = t >> 5;
    int lane = t & 31;
    unsigned long long key = keys[q];
    int idx = (int)(key & (unsigned long long)(N_LIDAR - 1));
    out[q * (D_FEAT / 4) + lane] = feat[idx * (D_FEAT / 4) + lane];
}

extern "C" void kernel_launch(void* const* d_in, const int* in_sizes, int n_in,
                              void* d_out, int out_size, void* d_ws, size_t ws_size,
                              hipStream_t stream) {
    const float* pts      = (const float*)d_in[0];   // (1,1024,32,3)
    const float* lidar    = (const float*)d_in[1];   // (1,8192,3)
    const float* features = (const float*)d_in[2];   // (1,8192,128)
    float* out = (float*)d_out;                      // (1,1024,32,128)

    char* ws = (char*)d_ws;
    unsigned long long* keys = (unsigned long long*)(ws + WS_KEYS);
    unsigned* gmin = (unsigned*)(ws + WS_GMIN);
    short* Atab = (short*)(ws + WS_ATAB);
    short* Btab = (short*)(ws + WS_BTAB);
    float4* qpack = (float4*)(ws + WS_QPK);
    float4* cpack = (float4*)(ws + WS_CPK);

    prep_kernel<<<N_QBLK, BLOCK, 0, stream>>>(pts, lidar, Atab, Btab,
                                              qpack, cpack, gmin, keys);
    p1_kernel<<<dim3(N_QBLK, NSEG1), BLOCK, 0, stream>>>(Atab, Btab, gmin);
    p2_kernel<<<dim3(N_QBLK, NSEG2), BLOCK, 0, stream>>>(Atab, Btab, gmin,
                                                         qpack, cpack, keys);
    gather_kernel<<<(M_QUERIES * 32) / BLOCK, BLOCK, 0, stream>>>(
        keys, (const float4*)features, (float4*)out);
}